// Round 1
// baseline (427.178 us; speedup 1.0000x reference)
//
#include <hip/hip_runtime.h>
#include <hip/hip_bf16.h>

// Problem constants
#define BH   64        // B*H rows
#define LSEQ 8192      // sequence length (softmax axis)
#define DDIM 64        // feature dim
#define NPOS (BH * LSEQ)   // 524288 positions

typedef __attribute__((ext_vector_type(8))) short bf16x8;   // 8 bf16 (4 VGPRs)
typedef __attribute__((ext_vector_type(4))) float f32x4;

// fp32 -> bf16 (RNE), as raw short bits
__device__ inline short f2bf(float f) {
    unsigned u = __builtin_bit_cast(unsigned, f);
    unsigned r = (u + 0x7FFFu + ((u >> 16) & 1u)) >> 16;
    return (short)r;
}
__device__ inline float bf2f(short s) {
    unsigned u = ((unsigned)(unsigned short)s) << 16;
    return __builtin_bit_cast(float, u);
}

// split 8 floats into bf16 hi + bf16 residual lo (hi+lo ~ fp32-accurate)
__device__ inline void split8(const float* f, bf16x8& hi, bf16x8& lo) {
#pragma unroll
    for (int j = 0; j < 8; j++) {
        short h = f2bf(f[j]);
        hi[j] = h;
        lo[j] = f2bf(f[j] - bf2f(h));
    }
}

__device__ inline float tanh_fast(float x) {
    // tanh(x) = 1 - 2/(exp(2x)+1); saturates correctly at +/-inf of exp
    float ex = __expf(2.f * x);
    return 1.f - 2.f * __builtin_amdgcn_rcpf(ex + 1.f);
}

// ---------------------------------------------------------------------------
// K1: e[p] = va . tanh(Wa q_p + Ua k_p + (Wa_b + Ua_b)) + va_b
// One wave computes a 16-position tile via mfma_f32_16x16x32_bf16.
//   A = [16 pos x 32 k] from q (or k), split hi/lo bf16
//   B = [32 k x 16 n]  = W[n][k] (plain bf16), 4 N-tiles cover 64 dims
//   D[row=pos_local][col=n_local], row = quad*4+reg, col = lane&15
// ---------------------------------------------------------------------------
__global__ __launch_bounds__(256) void score_kernel(
    const float* __restrict__ q, const float* __restrict__ k,
    const float* __restrict__ Waw, const float* __restrict__ Wab,
    const float* __restrict__ Uaw, const float* __restrict__ Uab,
    const float* __restrict__ vaw, const float* __restrict__ vab_p,
    float* __restrict__ e_out)
{
    const int lane = threadIdx.x & 63;
    const int m    = lane & 15;     // A-row / D-col index
    const int quad = lane >> 4;     // 0..3
    const int wgl  = blockIdx.x * 4 + (threadIdx.x >> 6);   // global wave id

    // --- per-wave constant fragments: B = W[n][k] for 4 n-tiles x 2 k-steps
    bf16x8 bwa[4][2], bua[4][2];
    float bias_s[4], vav[4];
#pragma unroll
    for (int t = 0; t < 4; t++) {
        const int n = t * 16 + m;
        bias_s[t] = Wab[n] + Uab[n];
        vav[t]    = vaw[n];
#pragma unroll
        for (int s = 0; s < 2; s++) {
            const int k0 = s * 32 + quad * 8;
            const float4 wA = ((const float4*)(Waw + n * 64 + k0))[0];
            const float4 wB = ((const float4*)(Waw + n * 64 + k0))[1];
            const float4 uA = ((const float4*)(Uaw + n * 64 + k0))[0];
            const float4 uB = ((const float4*)(Uaw + n * 64 + k0))[1];
            float wf[8] = {wA.x, wA.y, wA.z, wA.w, wB.x, wB.y, wB.z, wB.w};
            float uf[8] = {uA.x, uA.y, uA.z, uA.w, uB.x, uB.y, uB.z, uB.w};
            bf16x8 wv, uv;
#pragma unroll
            for (int j = 0; j < 8; j++) { wv[j] = f2bf(wf[j]); uv[j] = f2bf(uf[j]); }
            bwa[t][s] = wv;
            bua[t][s] = uv;
        }
    }
    const float vab = vab_p[0];

#pragma unroll 1
    for (int ti = 0; ti < 4; ++ti) {
        const long tile = (long)wgl * 4 + ti;
        const long p0   = tile * 16;

        f32x4 acc[4];
#pragma unroll
        for (int t = 0; t < 4; t++) acc[t] = (f32x4){0.f, 0.f, 0.f, 0.f};

#pragma unroll
        for (int s = 0; s < 2; s++) {
            const size_t off = (size_t)(p0 + m) * 64 + s * 32 + quad * 8;
            const float4 qa = ((const float4*)(q + off))[0];
            const float4 qb = ((const float4*)(q + off))[1];
            const float4 ka = ((const float4*)(k + off))[0];
            const float4 kb = ((const float4*)(k + off))[1];
            float qf[8] = {qa.x, qa.y, qa.z, qa.w, qb.x, qb.y, qb.z, qb.w};
            float kf[8] = {ka.x, ka.y, ka.z, ka.w, kb.x, kb.y, kb.z, kb.w};
            bf16x8 qhi, qlo, khi, klo;
            split8(qf, qhi, qlo);
            split8(kf, khi, klo);
#pragma unroll
            for (int t = 0; t < 4; t++) {
                acc[t] = __builtin_amdgcn_mfma_f32_16x16x32_bf16(qhi, bwa[t][s], acc[t], 0, 0, 0);
                acc[t] = __builtin_amdgcn_mfma_f32_16x16x32_bf16(qlo, bwa[t][s], acc[t], 0, 0, 0);
                acc[t] = __builtin_amdgcn_mfma_f32_16x16x32_bf16(khi, bua[t][s], acc[t], 0, 0, 0);
                acc[t] = __builtin_amdgcn_mfma_f32_16x16x32_bf16(klo, bua[t][s], acc[t], 0, 0, 0);
            }
        }

        // epilogue: bias + tanh + va-dot, reduce over 64 dims
        float c[4] = {0.f, 0.f, 0.f, 0.f};
#pragma unroll
        for (int t = 0; t < 4; t++) {
#pragma unroll
            for (int r = 0; r < 4; r++) {
                float x = acc[t][r] + bias_s[t];
                c[r] += vav[t] * tanh_fast(x);
            }
        }
        // sum over the 16 lanes of each quad (n-dimension)
#pragma unroll
        for (int r = 0; r < 4; r++) {
#pragma unroll
            for (int off2 = 1; off2 < 16; off2 <<= 1)
                c[r] += __shfl_xor(c[r], off2, 16);
        }
        if (m == 0) {
            float4 ev = make_float4(c[0] + vab, c[1] + vab, c[2] + vab, c[3] + vab);
            *((float4*)(e_out + p0 + quad * 4)) = ev;
        }
    }
}

// ---------------------------------------------------------------------------
// K2: in-place masked softmax over each length-8192 row of e (64 rows).
// One 1024-thread block per row; each thread owns 8 elements (2 x float4).
// ---------------------------------------------------------------------------
__global__ __launch_bounds__(1024) void softmax_kernel(
    const int* __restrict__ mask, float* __restrict__ e)
{
    const int row  = blockIdx.x;
    const size_t base = (size_t)row * LSEQ;
    const int tid  = threadIdx.x;
    const int lane = tid & 63;
    const int wv   = tid >> 6;
    __shared__ float redmax[16];
    __shared__ float redsum[16];

    float4 e0 = ((const float4*)(e + base))[tid];
    float4 e1 = ((const float4*)(e + base))[1024 + tid];
    int4  m0 = ((const int4*)(mask + base))[tid];
    int4  m1 = ((const int4*)(mask + base))[1024 + tid];

    float em[8];
    em[0] = m0.x ? e0.x : -10000.f;
    em[1] = m0.y ? e0.y : -10000.f;
    em[2] = m0.z ? e0.z : -10000.f;
    em[3] = m0.w ? e0.w : -10000.f;
    em[4] = m1.x ? e1.x : -10000.f;
    em[5] = m1.y ? e1.y : -10000.f;
    em[6] = m1.z ? e1.z : -10000.f;
    em[7] = m1.w ? e1.w : -10000.f;

    float lm = em[0];
#pragma unroll
    for (int j = 1; j < 8; j++) lm = fmaxf(lm, em[j]);
#pragma unroll
    for (int off = 32; off >= 1; off >>= 1) lm = fmaxf(lm, __shfl_xor(lm, off, 64));
    if (lane == 0) redmax[wv] = lm;
    __syncthreads();
    float M = redmax[0];
#pragma unroll
    for (int i = 1; i < 16; i++) M = fmaxf(M, redmax[i]);

    float ex[8];
    float ls = 0.f;
#pragma unroll
    for (int j = 0; j < 8; j++) { ex[j] = __expf(em[j] - M); ls += ex[j]; }
#pragma unroll
    for (int off = 32; off >= 1; off >>= 1) ls += __shfl_xor(ls, off, 64);
    if (lane == 0) redsum[wv] = ls;
    __syncthreads();
    float S = 0.f;
#pragma unroll
    for (int i = 0; i < 16; i++) S += redsum[i];
    const float inv = 1.f / S;

    float4 o0 = make_float4(ex[0] * inv, ex[1] * inv, ex[2] * inv, ex[3] * inv);
    float4 o1 = make_float4(ex[4] * inv, ex[5] * inv, ex[6] * inv, ex[7] * inv);
    ((float4*)(e + base))[tid]        = o0;
    ((float4*)(e + base))[1024 + tid] = o1;
}

// ---------------------------------------------------------------------------
// K3: out[p][d] = alpha[p] * v[p][d]   (pure streaming, float4)
// ---------------------------------------------------------------------------
__global__ __launch_bounds__(256) void scale_kernel(
    const float* __restrict__ v, const float* __restrict__ alpha,
    float* __restrict__ out)
{
    const size_t i = (size_t)blockIdx.x * 256 + threadIdx.x;   // float4 index
    float4 vv = ((const float4*)v)[i];
    const float a = alpha[i >> 4];   // 16 float4 groups per position (64 floats)
    float4 o = make_float4(a * vv.x, a * vv.y, a * vv.z, a * vv.w);
    ((float4*)out)[i] = o;
}

extern "C" void kernel_launch(void* const* d_in, const int* in_sizes, int n_in,
                              void* d_out, int out_size, void* d_ws, size_t ws_size,
                              hipStream_t stream) {
    const float* q    = (const float*)d_in[0];
    const float* k    = (const float*)d_in[1];
    const float* v    = (const float*)d_in[2];
    const int*   mask = (const int*)d_in[3];
    const float* Waw  = (const float*)d_in[4];
    const float* Wab  = (const float*)d_in[5];
    const float* Uaw  = (const float*)d_in[6];
    const float* Uab  = (const float*)d_in[7];
    const float* vaw  = (const float*)d_in[8];
    const float* vab  = (const float*)d_in[9];
    float* out = (float*)d_out;

    float* e_buf = (float*)d_ws;   // NPOS floats = 2 MB scratch (scores -> alpha in-place)

    // K1: 32768 tiles of 16 positions; 4 waves/block, 4 tiles/wave -> 2048 blocks
    score_kernel<<<2048, 256, 0, stream>>>(q, k, Waw, Wab, Uaw, Uab, vaw, vab, e_buf);
    // K2: one block per (b,h) row
    softmax_kernel<<<BH, 1024, 0, stream>>>(mask, e_buf);
    // K3: 33554432 floats / 4 per thread / 256 per block = 32768 blocks
    scale_kernel<<<NPOS * DDIM / 4 / 256, 256, 0, stream>>>(v, e_buf, out);
}

// Round 2
// 418.535 us; speedup vs baseline: 1.0206x; 1.0206x over previous
//
#include <hip/hip_runtime.h>
#include <hip/hip_bf16.h>

#define BH   64
#define LSEQ 8192
#define DDIM 64
#define NPOS (BH * LSEQ)          // 524288 positions
#define NT4  (NPOS * DDIM / 4)    // 8388608 float4s in v/out

typedef __attribute__((ext_vector_type(8))) short bf16x8;
typedef __attribute__((ext_vector_type(4))) float f32x4;

__device__ inline short f2bf(float f) {
    unsigned u = __builtin_bit_cast(unsigned, f);
    unsigned r = (u + 0x7FFFu + ((u >> 16) & 1u)) >> 16;
    return (short)r;
}
__device__ inline float bf2f(short s) {
    unsigned u = ((unsigned)(unsigned short)s) << 16;
    return __builtin_bit_cast(float, u);
}
__device__ inline void split8(const float* f, bf16x8& hi, bf16x8& lo) {
#pragma unroll
    for (int j = 0; j < 8; j++) {
        short h = f2bf(f[j]);
        hi[j] = h;
        lo[j] = f2bf(f[j] - bf2f(h));
    }
}
__device__ inline float tanh_fast(float x) {
    float ex = __expf(2.f * x);
    return 1.f - 2.f * __builtin_amdgcn_rcpf(ex + 1.f);
}

// ---------------------------------------------------------------------------
// K1: e[p] = mask ? va.tanh(Wa q + Ua k + bias) + va_b : -10000
// One wave = 16 positions per tile, 4 tiles, software-pipelined with two
// register buffers so >=8 float4 loads stay in flight while computing.
// ---------------------------------------------------------------------------
__global__ __launch_bounds__(256) void score_kernel(
    const float* __restrict__ q, const float* __restrict__ k,
    const int*   __restrict__ mask,
    const float* __restrict__ Waw, const float* __restrict__ Wab,
    const float* __restrict__ Uaw, const float* __restrict__ Uab,
    const float* __restrict__ vaw, const float* __restrict__ vab_p,
    float* __restrict__ e_out)
{
    const int lane = threadIdx.x & 63;
    const int m    = lane & 15;
    const int quad = lane >> 4;
    const int wgl  = blockIdx.x * 4 + (threadIdx.x >> 6);
    const long t0  = (long)wgl * 4;

    // per-wave constant weight fragments (bf16), biases, va
    bf16x8 bwa[4][2], bua[4][2];
    float bias_s[4], vav[4];
#pragma unroll
    for (int t = 0; t < 4; t++) {
        const int n = t * 16 + m;
        bias_s[t] = Wab[n] + Uab[n];
        vav[t]    = vaw[n];
#pragma unroll
        for (int s = 0; s < 2; s++) {
            const int k0 = s * 32 + quad * 8;
            const float4 wA = ((const float4*)(Waw + n * 64 + k0))[0];
            const float4 wB = ((const float4*)(Waw + n * 64 + k0))[1];
            const float4 uA = ((const float4*)(Uaw + n * 64 + k0))[0];
            const float4 uB = ((const float4*)(Uaw + n * 64 + k0))[1];
            float wf[8] = {wA.x, wA.y, wA.z, wA.w, wB.x, wB.y, wB.z, wB.w};
            float uf[8] = {uA.x, uA.y, uA.z, uA.w, uB.x, uB.y, uB.z, uB.w};
            bf16x8 wv, uv;
#pragma unroll
            for (int j = 0; j < 8; j++) { wv[j] = f2bf(wf[j]); uv[j] = f2bf(uf[j]); }
            bwa[t][s] = wv;
            bua[t][s] = uv;
        }
    }
    const float vab = vab_p[0];

    float4 A[8], B[8];
    int4 mkA, mkB;

    auto issue = [&](float4 (&buf)[8], int4& mk, long tile) {
        mk = ((const int4*)mask)[tile * 4 + quad];
        const size_t off = (size_t)(tile * 16 + m) * 64 + quad * 8;
        buf[0] = *((const float4*)(q + off));
        buf[1] = *((const float4*)(q + off + 4));
        buf[2] = *((const float4*)(k + off));
        buf[3] = *((const float4*)(k + off + 4));
        buf[4] = *((const float4*)(q + off + 32));
        buf[5] = *((const float4*)(q + off + 36));
        buf[6] = *((const float4*)(k + off + 32));
        buf[7] = *((const float4*)(k + off + 36));
    };

    auto compute = [&](const float4 (&buf)[8], const int4& mk, long tile) {
        f32x4 acc[4];
#pragma unroll
        for (int t = 0; t < 4; t++) acc[t] = (f32x4){0.f, 0.f, 0.f, 0.f};
#pragma unroll
        for (int s = 0; s < 2; s++) {
            const float4 qa = buf[s * 4 + 0], qb = buf[s * 4 + 1];
            const float4 ka = buf[s * 4 + 2], kb = buf[s * 4 + 3];
            float qf[8] = {qa.x, qa.y, qa.z, qa.w, qb.x, qb.y, qb.z, qb.w};
            float kf[8] = {ka.x, ka.y, ka.z, ka.w, kb.x, kb.y, kb.z, kb.w};
            bf16x8 qhi, qlo, khi, klo;
            split8(qf, qhi, qlo);
            split8(kf, khi, klo);
#pragma unroll
            for (int t = 0; t < 4; t++) {
                acc[t] = __builtin_amdgcn_mfma_f32_16x16x32_bf16(qhi, bwa[t][s], acc[t], 0, 0, 0);
                acc[t] = __builtin_amdgcn_mfma_f32_16x16x32_bf16(qlo, bwa[t][s], acc[t], 0, 0, 0);
                acc[t] = __builtin_amdgcn_mfma_f32_16x16x32_bf16(khi, bua[t][s], acc[t], 0, 0, 0);
                acc[t] = __builtin_amdgcn_mfma_f32_16x16x32_bf16(klo, bua[t][s], acc[t], 0, 0, 0);
            }
        }
        float c[4] = {0.f, 0.f, 0.f, 0.f};
#pragma unroll
        for (int t = 0; t < 4; t++) {
#pragma unroll
            for (int r = 0; r < 4; r++)
                c[r] += vav[t] * tanh_fast(acc[t][r] + bias_s[t]);
        }
#pragma unroll
        for (int r = 0; r < 4; r++) {
#pragma unroll
            for (int off2 = 1; off2 < 16; off2 <<= 1)
                c[r] += __shfl_xor(c[r], off2, 16);
        }
        if (m == 0) {
            float4 ev;
            ev.x = mk.x ? c[0] + vab : -10000.f;
            ev.y = mk.y ? c[1] + vab : -10000.f;
            ev.z = mk.z ? c[2] + vab : -10000.f;
            ev.w = mk.w ? c[3] + vab : -10000.f;
            *((float4*)(e_out + tile * 16 + quad * 4)) = ev;
        }
    };

    // software pipeline: 2 buffers, 4 tiles
    issue(A, mkA, t0 + 0);
    issue(B, mkB, t0 + 1);
    compute(A, mkA, t0 + 0);
    issue(A, mkA, t0 + 2);
    compute(B, mkB, t0 + 1);
    issue(B, mkB, t0 + 3);
    compute(A, mkA, t0 + 2);
    compute(B, mkB, t0 + 3);
}

// ---------------------------------------------------------------------------
// K2: per-row stats: M = max(e), invS = 1/sum(exp(e-M)). Mask already in e.
// ---------------------------------------------------------------------------
__global__ __launch_bounds__(1024) void rowstat_kernel(
    const float* __restrict__ e, float* __restrict__ stats)
{
    const int row = blockIdx.x;
    const size_t base = (size_t)row * LSEQ;
    const int tid  = threadIdx.x;
    const int lane = tid & 63;
    const int wv   = tid >> 6;
    __shared__ float redmax[16];
    __shared__ float redsum[16];

    float4 e0 = ((const float4*)(e + base))[tid];
    float4 e1 = ((const float4*)(e + base))[1024 + tid];
    float em[8] = {e0.x, e0.y, e0.z, e0.w, e1.x, e1.y, e1.z, e1.w};

    float lm = em[0];
#pragma unroll
    for (int j = 1; j < 8; j++) lm = fmaxf(lm, em[j]);
#pragma unroll
    for (int off = 32; off >= 1; off >>= 1) lm = fmaxf(lm, __shfl_xor(lm, off, 64));
    if (lane == 0) redmax[wv] = lm;
    __syncthreads();
    float M = redmax[0];
#pragma unroll
    for (int i = 1; i < 16; i++) M = fmaxf(M, redmax[i]);

    float ls = 0.f;
#pragma unroll
    for (int j = 0; j < 8; j++) ls += __expf(em[j] - M);
#pragma unroll
    for (int off = 32; off >= 1; off >>= 1) ls += __shfl_xor(ls, off, 64);
    if (lane == 0) redsum[wv] = ls;
    __syncthreads();
    if (tid == 0) {
        float S = 0.f;
#pragma unroll
        for (int i = 0; i < 16; i++) S += redsum[i];
        stats[row * 2]     = M;
        stats[row * 2 + 1] = 1.f / S;
    }
}

// ---------------------------------------------------------------------------
// K3: out[p][d] = exp(e[p]-M[row])*invS[row] * v[p][d]; 2 float4/thread.
// ---------------------------------------------------------------------------
__global__ __launch_bounds__(256) void scale_kernel(
    const float* __restrict__ v, const float* __restrict__ e,
    const float* __restrict__ stats, float* __restrict__ out)
{
    const size_t i0 = (size_t)blockIdx.x * 256 + threadIdx.x;
    const size_t i1 = i0 + (size_t)(NT4 / 2);

    // issue all independent loads first
    float4 v0 = ((const float4*)v)[i0];
    float4 v1 = ((const float4*)v)[i1];
    const size_t p0 = i0 >> 4, p1 = i1 >> 4;
    float e0 = e[p0], e1 = e[p1];
    const size_t r0 = p0 >> 13, r1 = p1 >> 13;
    float M0 = stats[r0 * 2], I0 = stats[r0 * 2 + 1];
    float M1 = stats[r1 * 2], I1 = stats[r1 * 2 + 1];

    float a0 = __expf(e0 - M0) * I0;
    float a1 = __expf(e1 - M1) * I1;
    float4 o0 = make_float4(a0 * v0.x, a0 * v0.y, a0 * v0.z, a0 * v0.w);
    float4 o1 = make_float4(a1 * v1.x, a1 * v1.y, a1 * v1.z, a1 * v1.w);
    ((float4*)out)[i0] = o0;
    ((float4*)out)[i1] = o1;
}

extern "C" void kernel_launch(void* const* d_in, const int* in_sizes, int n_in,
                              void* d_out, int out_size, void* d_ws, size_t ws_size,
                              hipStream_t stream) {
    const float* q    = (const float*)d_in[0];
    const float* k    = (const float*)d_in[1];
    const float* v    = (const float*)d_in[2];
    const int*   mask = (const int*)d_in[3];
    const float* Waw  = (const float*)d_in[4];
    const float* Wab  = (const float*)d_in[5];
    const float* Uaw  = (const float*)d_in[6];
    const float* Uab  = (const float*)d_in[7];
    const float* vaw  = (const float*)d_in[8];
    const float* vab  = (const float*)d_in[9];
    float* out = (float*)d_out;

    float* e_buf = (float*)d_ws;                  // NPOS floats (2 MB)
    float* stats = (float*)d_ws + NPOS;           // 128 floats (M, invS per row)

    score_kernel<<<2048, 256, 0, stream>>>(q, k, mask, Waw, Wab, Uaw, Uab, vaw, vab, e_buf);
    rowstat_kernel<<<BH, 1024, 0, stream>>>(e_buf, stats);
    scale_kernel<<<NT4 / 2 / 256, 256, 0, stream>>>(v, e_buf, stats, out);
}